// Round 7
// baseline (107.595 us; speedup 1.0000x reference)
//
#include <hip/hip_runtime.h>

#define HH 128
#define WW 128
#define HWSZ (HH * WW)   // 16384
#define CC 64
#define BB 2
#define KK 7
#define K2 49
#define PSTRIDE 52       // padded k2 stride for At (13 float4, 16B-aligned rows)
#define PADROW 140       // [3 pad][64 even][3 pad][3 pad][64 odd][3 pad]
#define EV_OFF 3
#define OD_OFF 73
#define ASLICE ((size_t)BB * HWSZ * PSTRIDE)   // 1,703,936 floats

__device__ __forceinline__ int clampi(int v, int lo, int hi) {
    return v < lo ? lo : (v > hi ? hi : v);
}

// unaligned-safe 16B load (4B-aligned dwordx4 is legal on gfx950 global)
__device__ __forceinline__ void ld4u(float* dst, const float* src) {
    __builtin_memcpy(dst, src, 16);
}

// ---------------------------------------------------------------------------
// K1: K/Q/V = relu(W @ x). Grid 1024 = xcd(8) x [pb16 x og8].
// K,V parity-split+padded (PADROW); Q transposed Qt[p][64] into d_out.
// ---------------------------------------------------------------------------
__global__ __launch_bounds__(256) void kqv_kernel(
    const float* __restrict__ x,  const float* __restrict__ Wk,
    const float* __restrict__ Wq, const float* __restrict__ Wv,
    float* __restrict__ Kp, float* __restrict__ Qt, float* __restrict__ Vp)
{
    const int xcd = blockIdx.x & 7;
    const int s   = blockIdx.x >> 3;          // 0..127
    const int pb  = xcd * 16 + (s & 15);      // 0..127
    const int og  = s >> 4;                   // 0..7
    const int p   = pb * 256 + threadIdx.x;   // 0..32767
    const int b   = p >> 14;
    const int hw  = p & 16383;
    const int h   = hw >> 7;
    const int w   = hw & 127;
    const int o0  = og * 8;
    const float* xp = x + (size_t)b * CC * HWSZ + hw;

    float aK[8], aQ[8], aV[8];
#pragma unroll
    for (int i = 0; i < 8; ++i) { aK[i] = 0.f; aQ[i] = 0.f; aV[i] = 0.f; }

#pragma unroll 4
    for (int c = 0; c < CC; ++c) {
        const float xv = xp[(size_t)c * HWSZ];
#pragma unroll
        for (int i = 0; i < 8; ++i) {
            aK[i] = fmaf(Wk[(o0 + i) * CC + c], xv, aK[i]);
            aQ[i] = fmaf(Wq[(o0 + i) * CC + c], xv, aQ[i]);
            aV[i] = fmaf(Wv[(o0 + i) * CC + c], xv, aV[i]);
        }
    }

    const int slot = ((w & 1) ? OD_OFF : EV_OFF) + (w >> 1);
#pragma unroll
    for (int i = 0; i < 8; ++i) {
        const float kv = fmaxf(aK[i], 0.f);
        const float vv = fmaxf(aV[i], 0.f);
        float* krow = Kp + ((size_t)(b * CC + o0 + i) * HH + h) * PADROW;
        float* vrow = Vp + ((size_t)(b * CC + o0 + i) * HH + h) * PADROW;
        krow[slot] = kv;
        vrow[slot] = vv;
        if (w == 0) {        // replicate-pad: pos<0 clamps to index 0
#pragma unroll
            for (int t = 0; t < 3; ++t) {
                krow[t] = kv; krow[70 + t] = kv;
                vrow[t] = vv; vrow[70 + t] = vv;
            }
        }
        if (w == 127) {      // pos>127 clamps to index 127
#pragma unroll
            for (int t = 0; t < 3; ++t) {
                krow[67 + t] = kv; krow[137 + t] = kv;
                vrow[67 + t] = vv; vrow[137 + t] = vv;
            }
        }
    }

    float4* qtv = (float4*)(Qt + (size_t)p * CC + o0);
    qtv[0] = make_float4(fmaxf(aQ[0], 0.f), fmaxf(aQ[1], 0.f),
                         fmaxf(aQ[2], 0.f), fmaxf(aQ[3], 0.f));
    qtv[1] = make_float4(fmaxf(aQ[4], 0.f), fmaxf(aQ[5], 0.f),
                         fmaxf(aQ[6], 0.f), fmaxf(aQ[7], 0.f));
}

// ---------------------------------------------------------------------------
// K2: partial scores, channel-halved. Grid 3584 = xcd(8) x [half2 x bh32 x i7],
// 128 thr, no LDS, no barriers. Half h covers c in [32h, 32h+32); writes its
// own At slice (disjoint -> race-free). 28 waves/CU.
// ---------------------------------------------------------------------------
__global__ __launch_bounds__(128) void score_kernel(
    const float* __restrict__ Kp, const float* __restrict__ Qt,
    float* __restrict__ At)
{
    const int xcd  = blockIdx.x & 7;
    const int s    = blockIdx.x >> 3;       // 0..447
    const int half = s & 1;
    const int t    = s >> 1;                // 0..223
    const int bh   = xcd * 32 + t / 7;      // 0..255
    const int i    = t % 7;
    const int w    = threadIdx.x;           // 0..127
    const int h    = bh & 127;
    const int b    = bh >> 7;
    const int hr   = clampi(h + 2 * i - 6, 0, HH - 1);
    const int p    = b * HWSZ + h * WW + w;
    const int c0b  = half * 32;

    const float* Qp = Qt + (size_t)p * CC + c0b;
    const float* Kbase = Kp + ((size_t)((b * CC + c0b) * HH) + hr) * PADROW
                         + ((w & 1) ? OD_OFF : EV_OFF) + ((w >> 1) - 3);
    const size_t cstride = (size_t)HH * PADROW;

    float sc[KK];
#pragma unroll
    for (int j = 0; j < KK; ++j) sc[j] = 0.f;

#pragma unroll 2
    for (int c4 = 0; c4 < 32; c4 += 4) {
        const float4 q4 = *(const float4*)(Qp + c4);
        const float qv[4] = {q4.x, q4.y, q4.z, q4.w};
#pragma unroll
        for (int cc = 0; cc < 4; ++cc) {
            const float* row = Kbase + (size_t)(c4 + cc) * cstride;
            float kv[8];
            ld4u(kv, row);
            ld4u(kv + 4, row + 4);
#pragma unroll
            for (int j = 0; j < KK; ++j)
                sc[j] = fmaf(kv[j], qv[cc], sc[j]);
        }
    }

    float* Ap = At + (size_t)half * ASLICE + (size_t)p * PSTRIDE + i * KK;
#pragma unroll
    for (int j = 0; j < KK; ++j) Ap[j] = sc[j];
}

// ---------------------------------------------------------------------------
// K2.5: softmax over 49: P = softmax(At0 + At1), written into slice 0.
// Grid 512 x 64 thr (1 wave). Vectorized 13 float4 in/out per slice.
// Sum order (half0 + half1) matches rounds 4/5 bitwise.
// ---------------------------------------------------------------------------
__global__ __launch_bounds__(64) void softmax_kernel(float* __restrict__ At)
{
    const int p = blockIdx.x * 64 + threadIdx.x;   // 0..32767
    float* A0 = At + (size_t)p * PSTRIDE;
    const float* A1 = A0 + ASLICE;

    float pr[52], q[52];
#pragma unroll
    for (int t = 0; t < 13; ++t) {
        ((float4*)pr)[t] = ((const float4*)A0)[t];
        ((float4*)q)[t]  = ((const float4*)A1)[t];
    }
#pragma unroll
    for (int k = 0; k < K2; ++k) pr[k] += q[k];

    float m = pr[0];
#pragma unroll
    for (int k = 1; k < K2; ++k) m = fmaxf(m, pr[k]);
    float sum = 0.f;
#pragma unroll
    for (int k = 0; k < K2; ++k) { pr[k] = __expf(pr[k] - m); sum += pr[k]; }
    const float inv = 1.f / sum;
#pragma unroll
    for (int k = 0; k < K2; ++k) pr[k] *= inv;
    pr[49] = pr[50] = pr[51] = 0.f;

#pragma unroll
    for (int t = 0; t < 13; ++t) ((float4*)A0)[t] = ((const float4*)pr)[t];
}

// ---------------------------------------------------------------------------
// K3: V-aggregate with ready probabilities P (At slice 0). Grid 2048 =
// xcd(8) x [bh32 x cg8], 256 thr = 128 w x 2 cs. No LDS, no barriers.
// ---------------------------------------------------------------------------
__global__ __launch_bounds__(256) void aggr_kernel(
    const float* __restrict__ Vp, const float* __restrict__ Pt,
    float* __restrict__ Ot)
{
    const int xcd = blockIdx.x & 7;
    const int s   = blockIdx.x >> 3;        // 0..255
    const int bh  = xcd * 32 + (s >> 3);
    const int cg  = s & 7;
    const int w   = threadIdx.x & 127;
    const int cs  = threadIdx.x >> 7;
    const int h   = bh & 127;
    const int b   = bh >> 7;
    const int p   = b * HWSZ + h * WW + w;

    float pr[52];
    const float4* Pv = (const float4*)(Pt + (size_t)p * PSTRIDE);
#pragma unroll
    for (int t = 0; t < 13; ++t) ((float4*)pr)[t] = Pv[t];

    int hn[KK];
#pragma unroll
    for (int i = 0; i < KK; ++i) hn[i] = clampi(h + 2 * i - 6, 0, HH - 1);

    const int poff = ((w & 1) ? OD_OFF : EV_OFF) + ((w >> 1) - 3);
    const int c0   = cg * 8 + cs * 4;
    float acc[4] = {0.f, 0.f, 0.f, 0.f};
#pragma unroll
    for (int cc = 0; cc < 4; ++cc) {
        const float* vch = Vp + (size_t)(b * CC + c0 + cc) * HH * PADROW;
#pragma unroll
        for (int i = 0; i < KK; ++i) {
            const float* row = vch + (size_t)hn[i] * PADROW + poff;
            float vv[8];
            ld4u(vv, row);
            ld4u(vv + 4, row + 4);
#pragma unroll
            for (int j = 0; j < KK; ++j)
                acc[cc] = fmaf(vv[j], pr[i * KK + j], acc[cc]);
        }
    }
    *(float4*)(Ot + (size_t)p * CC + c0) =
        make_float4(acc[0], acc[1], acc[2], acc[3]);
}

// ---------------------------------------------------------------------------
// K4: out = Wt @ O + x. Grid 1024 = xcd(8) x [pb16 x og8].
// ---------------------------------------------------------------------------
__global__ __launch_bounds__(256) void wt_kernel(
    const float* __restrict__ Ot, const float* __restrict__ x,
    const float* __restrict__ Wt, float* __restrict__ out)
{
    const int xcd = blockIdx.x & 7;
    const int s   = blockIdx.x >> 3;        // 0..127
    const int pb  = xcd * 16 + (s & 15);
    const int og  = s >> 4;
    const int p   = pb * 256 + threadIdx.x;
    const int b   = p >> 14;
    const int hw  = p & 16383;
    const int o0  = og * 8;

    float fin[8];
#pragma unroll
    for (int i = 0; i < 8; ++i)
        fin[i] = x[((size_t)b * CC + o0 + i) * HWSZ + hw];

    const float4* ov = (const float4*)(Ot + (size_t)p * CC);
#pragma unroll
    for (int c4 = 0; c4 < 16; ++c4) {
        const float4 o4 = ov[c4];
        const float oc[4] = {o4.x, o4.y, o4.z, o4.w};
#pragma unroll
        for (int cc = 0; cc < 4; ++cc) {
            const int c = c4 * 4 + cc;
#pragma unroll
            for (int i = 0; i < 8; ++i)
                fin[i] = fmaf(Wt[(o0 + i) * CC + c], oc[cc], fin[i]);
        }
    }

#pragma unroll
    for (int i = 0; i < 8; ++i)
        out[((size_t)b * CC + o0 + i) * HWSZ + hw] = fin[i];
}

// ---------------------------------------------------------------------------
extern "C" void kernel_launch(void* const* d_in, const int* in_sizes, int n_in,
                              void* d_out, int out_size, void* d_ws, size_t ws_size,
                              hipStream_t stream)
{
    const float* x  = (const float*)d_in[0];
    const float* Wk = (const float*)d_in[1];
    const float* Wq = (const float*)d_in[2];
    const float* Wv = (const float*)d_in[3];
    const float* Wt = (const float*)d_in[4];
    float* out = (float*)d_out;

    const size_t KP_ELEMS = (size_t)BB * CC * HH * PADROW;  // 2,293,760
    float* Kp = (float*)d_ws;
    float* Vp = Kp + KP_ELEMS;
    float* At = Vp + KP_ELEMS;       // 2 slices x 1,703,936 -> total 30.5 MB
    float* Qt = out;                 // d_out as scratch; dead before wt writes
    float* Ot = Kp;                  // Kp dead after score

    hipLaunchKernelGGL(kqv_kernel, dim3(1024), dim3(256), 0, stream,
                       x, Wk, Wq, Wv, Kp, Qt, Vp);
    hipLaunchKernelGGL(score_kernel, dim3(2 * BB * HH * KK), dim3(128), 0, stream,
                       Kp, Qt, At);
    hipLaunchKernelGGL(softmax_kernel, dim3(BB * HWSZ / 64), dim3(64), 0, stream,
                       At);
    hipLaunchKernelGGL(aggr_kernel, dim3(2048), dim3(256), 0, stream,
                       Vp, At, Ot);
    hipLaunchKernelGGL(wt_kernel, dim3(1024), dim3(256), 0, stream,
                       Ot, x, Wt, out);
}

// Round 8
// 100.720 us; speedup vs baseline: 1.0683x; 1.0683x over previous
//
#include <hip/hip_runtime.h>

#define HH 128
#define WW 128
#define HWSZ (HH * WW)   // 16384
#define CC 64
#define BB 2
#define KK 7
#define K2 49
#define PSTRIDE 52       // padded k2 stride for At (13 float4 rows)
#define PADROW 140       // [3 pad][64 even][3 pad][3 pad][64 odd][3 pad]
#define EV_OFF 3
#define OD_OFF 73

__device__ __forceinline__ int clampi(int v, int lo, int hi) {
    return v < lo ? lo : (v > hi ? hi : v);
}

// unaligned-safe 16B load (4B-aligned dwordx4 is legal on gfx950 global)
__device__ __forceinline__ void ld4u(float* dst, const float* src) {
    __builtin_memcpy(dst, src, 16);
}

// ---------------------------------------------------------------------------
// K1: K/Q/V = relu(W @ x). Grid 1024 = xcd(8) x [pb16 x og8].
// K,V parity-split+padded (PADROW); Q transposed Qt[p][64] into d_out.
// ---------------------------------------------------------------------------
__global__ __launch_bounds__(256) void kqv_kernel(
    const float* __restrict__ x,  const float* __restrict__ Wk,
    const float* __restrict__ Wq, const float* __restrict__ Wv,
    float* __restrict__ Kp, float* __restrict__ Qt, float* __restrict__ Vp)
{
    const int xcd = blockIdx.x & 7;
    const int s   = blockIdx.x >> 3;          // 0..127
    const int pb  = xcd * 16 + (s & 15);      // 0..127
    const int og  = s >> 4;                   // 0..7
    const int p   = pb * 256 + threadIdx.x;   // 0..32767
    const int b   = p >> 14;
    const int hw  = p & 16383;
    const int h   = hw >> 7;
    const int w   = hw & 127;
    const int o0  = og * 8;
    const float* xp = x + (size_t)b * CC * HWSZ + hw;

    float aK[8], aQ[8], aV[8];
#pragma unroll
    for (int i = 0; i < 8; ++i) { aK[i] = 0.f; aQ[i] = 0.f; aV[i] = 0.f; }

#pragma unroll 4
    for (int c = 0; c < CC; ++c) {
        const float xv = xp[(size_t)c * HWSZ];
#pragma unroll
        for (int i = 0; i < 8; ++i) {
            aK[i] = fmaf(Wk[(o0 + i) * CC + c], xv, aK[i]);
            aQ[i] = fmaf(Wq[(o0 + i) * CC + c], xv, aQ[i]);
            aV[i] = fmaf(Wv[(o0 + i) * CC + c], xv, aV[i]);
        }
    }

    const int slot = ((w & 1) ? OD_OFF : EV_OFF) + (w >> 1);
#pragma unroll
    for (int i = 0; i < 8; ++i) {
        const float kv = fmaxf(aK[i], 0.f);
        const float vv = fmaxf(aV[i], 0.f);
        float* krow = Kp + ((size_t)(b * CC + o0 + i) * HH + h) * PADROW;
        float* vrow = Vp + ((size_t)(b * CC + o0 + i) * HH + h) * PADROW;
        krow[slot] = kv;
        vrow[slot] = vv;
        if (w == 0) {
#pragma unroll
            for (int t = 0; t < 3; ++t) {
                krow[t] = kv; krow[70 + t] = kv;
                vrow[t] = vv; vrow[70 + t] = vv;
            }
        }
        if (w == 127) {
#pragma unroll
            for (int t = 0; t < 3; ++t) {
                krow[67 + t] = kv; krow[137 + t] = kv;
                vrow[67 + t] = vv; vrow[137 + t] = vv;
            }
        }
    }

    float4* qtv = (float4*)(Qt + (size_t)p * CC + o0);
    qtv[0] = make_float4(fmaxf(aQ[0], 0.f), fmaxf(aQ[1], 0.f),
                         fmaxf(aQ[2], 0.f), fmaxf(aQ[3], 0.f));
    qtv[1] = make_float4(fmaxf(aQ[4], 0.f), fmaxf(aQ[5], 0.f),
                         fmaxf(aQ[6], 0.f), fmaxf(aQ[7], 0.f));
}

// ---------------------------------------------------------------------------
// K2: scores, source-row-centric. Block (b, hr) computes At[p(h,w)][i*7+j]
// for ALL (h,i) with clamp(h+2i-6)==hr -- the K-window load per (lane,chan)
// is shared across up to 4 pairs per pair-group (0.107 loads/FMA, 3x cut).
// 256 thr = 128 w x 2 pair-groups. Grid 256 = xcd(8) x 32. No LDS.
// ---------------------------------------------------------------------------
__global__ __launch_bounds__(256) void score_kernel(
    const float* __restrict__ Kp, const float* __restrict__ Qt,
    float* __restrict__ At)
{
    const int xcd = blockIdx.x & 7;
    const int s   = blockIdx.x >> 3;       // 0..31
    const int bhr = xcd * 32 + s;          // 0..255
    const int b   = bhr >> 7;
    const int hr  = bhr & 127;
    const int w   = threadIdx.x & 127;
    const int pg  = threadIdx.x >> 7;      // 0/1

    // (h,i) pair list served by source row hr (uniform across block)
    int ph[16], pi[16];
    int np = 0;
#pragma unroll
    for (int i = 0; i < 7; ++i) {
        const int h = hr + 6 - 2 * i;
        if (h >= 0 && h < HH) { ph[np] = h; pi[np] = i; ++np; }
    }
    if (hr == 0) {
        for (int i = 0; i < 3; ++i)
            for (int h = 0; h <= 5 - 2 * i; ++h) { ph[np] = h; pi[np] = i; ++np; }
    } else if (hr == HH - 1) {
        for (int i = 4; i < 7; ++i)
            for (int h = 134 - 2 * i; h < HH; ++h) { ph[np] = h; pi[np] = i; ++np; }
    }

    const int n0     = (np + 1) >> 1;
    const int pstart = pg ? n0 : 0;
    const int pend   = pg ? np : n0;

    const float* Kbase = Kp + ((size_t)(b * CC) * HH + hr) * PADROW
                         + ((w & 1) ? OD_OFF : EV_OFF) + ((w >> 1) - 3);
    const size_t cstride = (size_t)HH * PADROW;

    for (int p0 = pstart; p0 < pend; p0 += 4) {
        int pp[4], pidx[4];
#pragma unroll
        for (int u = 0; u < 4; ++u) {
            const int idx = (p0 + u < pend) ? (p0 + u) : pstart;
            pidx[u] = idx;
            pp[u] = b * HWSZ + ph[idx] * WW + w;
        }

        float sc[4][KK];
#pragma unroll
        for (int u = 0; u < 4; ++u)
#pragma unroll
            for (int j = 0; j < KK; ++j) sc[u][j] = 0.f;

        for (int c4 = 0; c4 < CC; c4 += 4) {
            float kv[4][8];
#pragma unroll
            for (int cc = 0; cc < 4; ++cc) {
                const float* row = Kbase + (size_t)(c4 + cc) * cstride;
                ld4u(kv[cc], row);
                ld4u(kv[cc] + 4, row + 4);
            }
            float4 qv[4];
#pragma unroll
            for (int u = 0; u < 4; ++u)
                qv[u] = *(const float4*)(Qt + (size_t)pp[u] * CC + c4);
#pragma unroll
            for (int u = 0; u < 4; ++u) {
                const float qs[4] = {qv[u].x, qv[u].y, qv[u].z, qv[u].w};
#pragma unroll
                for (int cc = 0; cc < 4; ++cc)
#pragma unroll
                    for (int j = 0; j < KK; ++j)
                        sc[u][j] = fmaf(kv[cc][j], qs[cc], sc[u][j]);
            }
        }

#pragma unroll
        for (int u = 0; u < 4; ++u) {
            if (p0 + u < pend) {
                float* Ap = At + (size_t)pp[u] * PSTRIDE + pi[pidx[u]] * KK;
#pragma unroll
                for (int j = 0; j < KK; ++j) Ap[j] = sc[u][j];
            }
        }
    }
}

// ---------------------------------------------------------------------------
// K3: fused softmax(49) + V-aggregate, 2 pixels (h, h+2) per thread so the
// 8 V-row windows serve 14 (pixel,i) uses (1.75x load cut). Grid 1024 =
// xcd(8) x [pair16 x cg8], 256 thr = 128 w x 2 cs. No LDS, no barriers.
// ---------------------------------------------------------------------------
__global__ __launch_bounds__(256) void aggr_kernel(
    const float* __restrict__ Vp, const float* __restrict__ At,
    float* __restrict__ Ot)
{
    const int xcd = blockIdx.x & 7;
    const int s   = blockIdx.x >> 3;        // 0..127
    const int cg  = s & 7;
    const int u   = s >> 3;                 // 0..15
    const int P   = xcd * 16 + u;           // 0..127 pair id
    const int b   = P >> 6;
    const int hpl = P & 63;
    const int ha  = (hpl >> 1) * 4 + (hpl & 1);   // pair (ha, ha+2)
    const int w   = threadIdx.x & 127;
    const int cs  = threadIdx.x >> 7;
    const int pa  = b * HWSZ + ha * WW + w;
    const int pb_ = pa + 2 * WW;

    float pra[52], prb[52];
    {
        const float4* Aa = (const float4*)(At + (size_t)pa * PSTRIDE);
        const float4* Ab = (const float4*)(At + (size_t)pb_ * PSTRIDE);
#pragma unroll
        for (int t = 0; t < 13; ++t) { ((float4*)pra)[t] = Aa[t]; ((float4*)prb)[t] = Ab[t]; }
        float ma = pra[0], mb = prb[0];
#pragma unroll
        for (int k = 1; k < K2; ++k) { ma = fmaxf(ma, pra[k]); mb = fmaxf(mb, prb[k]); }
        float sa = 0.f, sb = 0.f;
#pragma unroll
        for (int k = 0; k < K2; ++k) {
            pra[k] = __expf(pra[k] - ma); sa += pra[k];
            prb[k] = __expf(prb[k] - mb); sb += prb[k];
        }
        const float ia = 1.f / sa, ib = 1.f / sb;
#pragma unroll
        for (int k = 0; k < K2; ++k) { pra[k] *= ia; prb[k] *= ib; }
    }

    int rw[8];
#pragma unroll
    for (int t = 0; t < 8; ++t) rw[t] = clampi(ha - 6 + 2 * t, 0, HH - 1);

    const int poff = ((w & 1) ? OD_OFF : EV_OFF) + ((w >> 1) - 3);
    const int c0   = cg * 8 + cs * 4;
    float acc_a[4] = {0.f, 0.f, 0.f, 0.f};
    float acc_b[4] = {0.f, 0.f, 0.f, 0.f};
#pragma unroll
    for (int cc = 0; cc < 4; ++cc) {
        const float* vch = Vp + (size_t)(b * CC + c0 + cc) * HH * PADROW + poff;
#pragma unroll
        for (int t = 0; t < 8; ++t) {
            float vv[8];
            const float* row = vch + (size_t)rw[t] * PADROW;
            ld4u(vv, row);
            ld4u(vv + 4, row + 4);
            if (t < 7) {
#pragma unroll
                for (int j = 0; j < KK; ++j)
                    acc_a[cc] = fmaf(vv[j], pra[t * KK + j], acc_a[cc]);
            }
            if (t >= 1) {
#pragma unroll
                for (int j = 0; j < KK; ++j)
                    acc_b[cc] = fmaf(vv[j], prb[(t - 1) * KK + j], acc_b[cc]);
            }
        }
    }
    *(float4*)(Ot + (size_t)pa * CC + c0) =
        make_float4(acc_a[0], acc_a[1], acc_a[2], acc_a[3]);
    *(float4*)(Ot + (size_t)pb_ * CC + c0) =
        make_float4(acc_b[0], acc_b[1], acc_b[2], acc_b[3]);
}

// ---------------------------------------------------------------------------
// K4: out = Wt @ O + x. Grid 1024 = xcd(8) x [pb16 x og8].
// ---------------------------------------------------------------------------
__global__ __launch_bounds__(256) void wt_kernel(
    const float* __restrict__ Ot, const float* __restrict__ x,
    const float* __restrict__ Wt, float* __restrict__ out)
{
    const int xcd = blockIdx.x & 7;
    const int s   = blockIdx.x >> 3;        // 0..127
    const int pb  = xcd * 16 + (s & 15);
    const int og  = s >> 4;
    const int p   = pb * 256 + threadIdx.x;
    const int b   = p >> 14;
    const int hw  = p & 16383;
    const int o0  = og * 8;

    float fin[8];
#pragma unroll
    for (int i = 0; i < 8; ++i)
        fin[i] = x[((size_t)b * CC + o0 + i) * HWSZ + hw];

    const float4* ov = (const float4*)(Ot + (size_t)p * CC);
#pragma unroll
    for (int c4 = 0; c4 < 16; ++c4) {
        const float4 o4 = ov[c4];
        const float oc[4] = {o4.x, o4.y, o4.z, o4.w};
#pragma unroll
        for (int cc = 0; cc < 4; ++cc) {
            const int c = c4 * 4 + cc;
#pragma unroll
            for (int i = 0; i < 8; ++i)
                fin[i] = fmaf(Wt[(o0 + i) * CC + c], oc[cc], fin[i]);
        }
    }

#pragma unroll
    for (int i = 0; i < 8; ++i)
        out[((size_t)b * CC + o0 + i) * HWSZ + hw] = fin[i];
}

// ---------------------------------------------------------------------------
extern "C" void kernel_launch(void* const* d_in, const int* in_sizes, int n_in,
                              void* d_out, int out_size, void* d_ws, size_t ws_size,
                              hipStream_t stream)
{
    const float* x  = (const float*)d_in[0];
    const float* Wk = (const float*)d_in[1];
    const float* Wq = (const float*)d_in[2];
    const float* Wv = (const float*)d_in[3];
    const float* Wt = (const float*)d_in[4];
    float* out = (float*)d_out;

    const size_t KP_ELEMS = (size_t)BB * CC * HH * PADROW;  // 2,293,760
    float* Kp = (float*)d_ws;
    float* Vp = Kp + KP_ELEMS;
    float* At = Vp + KP_ELEMS;       // BB*HWSZ*52 -> total 25.2 MB
    float* Qt = out;                 // d_out as scratch; dead before wt writes
    float* Ot = Kp;                  // Kp dead after score

    hipLaunchKernelGGL(kqv_kernel, dim3(1024), dim3(256), 0, stream,
                       x, Wk, Wq, Wv, Kp, Qt, Vp);
    hipLaunchKernelGGL(score_kernel, dim3(BB * HH), dim3(256), 0, stream,
                       Kp, Qt, At);
    hipLaunchKernelGGL(aggr_kernel, dim3(1024), dim3(256), 0, stream,
                       Vp, At, Ot);
    hipLaunchKernelGGL(wt_kernel, dim3(1024), dim3(256), 0, stream,
                       Ot, x, Wt, out);
}

// Round 9
// 99.254 us; speedup vs baseline: 1.0840x; 1.0148x over previous
//
#include <hip/hip_runtime.h>
#include <hip/hip_bf16.h>

#define HH 128
#define WW 128
#define HWSZ (HH * WW)   // 16384
#define CC 64
#define BB 2
#define KK 7
#define K2 49
#define PSTRIDE 52       // padded k2 stride for At (13 float4 rows), fp32
#define ROWE 280         // bf16 elems/padded row: [Eph0 70][Eph1 70][Oph0 70][Oph1 70]

typedef unsigned int u32;

__device__ __forceinline__ int clampi(int v, int lo, int hi) {
    return v < lo ? lo : (v > hi ? hi : v);
}

__device__ __forceinline__ uint4 ld16(const __hip_bfloat16* src) {
    uint4 d; __builtin_memcpy(&d, src, 16); return d;   // 4B-aligned dwordx4
}

// 8 packed bf16 (4 dwords) -> 8 fp32. elem 2k = lo half of dword k.
__device__ __forceinline__ void unpack8(uint4 d, float* f) {
    f[0] = __uint_as_float(d.x << 16); f[1] = __uint_as_float(d.x & 0xffff0000u);
    f[2] = __uint_as_float(d.y << 16); f[3] = __uint_as_float(d.y & 0xffff0000u);
    f[4] = __uint_as_float(d.z << 16); f[5] = __uint_as_float(d.z & 0xffff0000u);
    f[6] = __uint_as_float(d.w << 16); f[7] = __uint_as_float(d.w & 0xffff0000u);
}

__device__ __forceinline__ unsigned short f2bf(float v) {
    __hip_bfloat16 b = __float2bfloat16(v);
    return *reinterpret_cast<unsigned short*>(&b);
}

// Store one K/V value into the phase-duplicated parity row + edge pads.
// Layout per (c,row): P[u]=clamped parity seq (70), P1[v]=P[v+1] (70), x2 parities.
__device__ __forceinline__ void store_kv(__hip_bfloat16* rowp, int w, float val) {
    const int parity = w & 1, t = w >> 1;
    const int pb = parity * 140;
    __hip_bfloat16 bv = __float2bfloat16(val);
    rowp[pb + 3 + t]  = bv;        // phase0: P[t+3]
    rowp[pb + 72 + t] = bv;        // phase1: P1[t+2]
    if (w == 0) {                  // pos<0 clamps to pixel 0 (both parities)
#pragma unroll
        for (int u = 0; u < 3; ++u) { rowp[u] = bv; rowp[140 + u] = bv; }
#pragma unroll
        for (int u = 0; u < 2; ++u) { rowp[70 + u] = bv; rowp[210 + u] = bv; }
    }
    if (w == 127) {                // pos>127 clamps to pixel 127 (both parities)
#pragma unroll
        for (int u = 0; u < 3; ++u) { rowp[67 + u] = bv; rowp[140 + 67 + u] = bv; }
#pragma unroll
        for (int u = 0; u < 4; ++u) { rowp[70 + 66 + u] = bv; rowp[210 + 66 + u] = bv; }
    }
}

// per-lane window offset: window = first 7 elems of one aligned 16B load
__device__ __forceinline__ int lane_off(int w) {
    const int parity = w & 1, t = w >> 1, phase = t & 1;
    return parity * 140 + phase * 70 + (t - phase);
}

// ---------------------------------------------------------------------------
// K1: K/Q/V = relu(W @ x). Grid 1024 = xcd(8) x [pb16 x og8].
// K,V -> bf16 phase-dup parity rows; Q -> bf16 Qt[p][64] in d_out.
// ---------------------------------------------------------------------------
__global__ __launch_bounds__(256) void kqv_kernel(
    const float* __restrict__ x,  const float* __restrict__ Wk,
    const float* __restrict__ Wq, const float* __restrict__ Wv,
    __hip_bfloat16* __restrict__ Kp, __hip_bfloat16* __restrict__ Qt,
    __hip_bfloat16* __restrict__ Vp)
{
    const int xcd = blockIdx.x & 7;
    const int s   = blockIdx.x >> 3;          // 0..127
    const int pb  = xcd * 16 + (s & 15);      // 0..127
    const int og  = s >> 4;                   // 0..7
    const int p   = pb * 256 + threadIdx.x;   // 0..32767
    const int b   = p >> 14;
    const int hw  = p & 16383;
    const int h   = hw >> 7;
    const int w   = hw & 127;
    const int o0  = og * 8;
    const float* xp = x + (size_t)b * CC * HWSZ + hw;

    float aK[8], aQ[8], aV[8];
#pragma unroll
    for (int i = 0; i < 8; ++i) { aK[i] = 0.f; aQ[i] = 0.f; aV[i] = 0.f; }

#pragma unroll 4
    for (int c = 0; c < CC; ++c) {
        const float xv = xp[(size_t)c * HWSZ];
#pragma unroll
        for (int i = 0; i < 8; ++i) {
            aK[i] = fmaf(Wk[(o0 + i) * CC + c], xv, aK[i]);
            aQ[i] = fmaf(Wq[(o0 + i) * CC + c], xv, aQ[i]);
            aV[i] = fmaf(Wv[(o0 + i) * CC + c], xv, aV[i]);
        }
    }

#pragma unroll
    for (int i = 0; i < 8; ++i) {
        __hip_bfloat16* krow = Kp + ((size_t)(b * CC + o0 + i) * HH + h) * ROWE;
        __hip_bfloat16* vrow = Vp + ((size_t)(b * CC + o0 + i) * HH + h) * ROWE;
        store_kv(krow, w, fmaxf(aK[i], 0.f));
        store_kv(vrow, w, fmaxf(aV[i], 0.f));
    }

    u32 qd[4];
#pragma unroll
    for (int i = 0; i < 4; ++i)
        qd[i] = (u32)f2bf(fmaxf(aQ[2 * i], 0.f)) |
                ((u32)f2bf(fmaxf(aQ[2 * i + 1], 0.f)) << 16);
    __builtin_memcpy(Qt + (size_t)p * CC + o0, qd, 16);   // 16B aligned
}

// ---------------------------------------------------------------------------
// K2: scores, source-row-centric. Block (b,hr), 512 thr = 128 w x 4 pg.
// Each pg quarter owns ~2-4 (h,i) pairs of the row-hr pair list; per channel
// ONE 16B bf16 window load serves all its pairs. Grid 256 -> 2048 waves.
// ---------------------------------------------------------------------------
__global__ __launch_bounds__(512) void score_kernel(
    const __hip_bfloat16* __restrict__ Kp, const __hip_bfloat16* __restrict__ Qt,
    float* __restrict__ At)
{
    const int xcd = blockIdx.x & 7;
    const int s   = blockIdx.x >> 3;       // 0..31
    const int bhr = xcd * 32 + s;          // 0..255
    const int b   = bhr >> 7;
    const int hr  = bhr & 127;
    const int w   = threadIdx.x & 127;
    const int pg  = threadIdx.x >> 7;      // 0..3

    int ph[16], pi[16];
    int np = 0;
#pragma unroll
    for (int i = 0; i < 7; ++i) {
        const int h = hr + 6 - 2 * i;
        if (h >= 0 && h < HH) { ph[np] = h; pi[np] = i; ++np; }
    }
    if (hr == 0) {
        for (int i = 0; i < 3; ++i)
            for (int h = 0; h <= 5 - 2 * i; ++h) { ph[np] = h; pi[np] = i; ++np; }
    } else if (hr == HH - 1) {
        for (int i = 4; i < 7; ++i)
            for (int h = 134 - 2 * i; h < HH; ++h) { ph[np] = h; pi[np] = i; ++np; }
    }

    const int pstart = (np * pg) >> 2;
    const int pend   = (np * (pg + 1)) >> 2;
    if (pstart >= pend) return;

    const __hip_bfloat16* Kbase =
        Kp + ((size_t)(b * CC) * HH + hr) * ROWE + lane_off(w);
    const size_t cstride = (size_t)HH * ROWE;

    for (int p0 = pstart; p0 < pend; p0 += 4) {
        int pp[4], pidx[4];
#pragma unroll
        for (int u = 0; u < 4; ++u) {
            const int idx = (p0 + u < pend) ? (p0 + u) : pstart;
            pidx[u] = idx;
            pp[u] = b * HWSZ + ph[idx] * WW + w;
        }

        float sc[4][KK];
#pragma unroll
        for (int u = 0; u < 4; ++u)
#pragma unroll
            for (int j = 0; j < KK; ++j) sc[u][j] = 0.f;

        for (int c4 = 0; c4 < CC; c4 += 4) {
            float kf[4][8];
#pragma unroll
            for (int cc = 0; cc < 4; ++cc)
                unpack8(ld16(Kbase + (size_t)(c4 + cc) * cstride), kf[cc]);
#pragma unroll
            for (int u = 0; u < 4; ++u) {
                u32 q2[2];
                __builtin_memcpy(q2, Qt + (size_t)pp[u] * CC + c4, 8);
                float qf[4];
                qf[0] = __uint_as_float(q2[0] << 16);
                qf[1] = __uint_as_float(q2[0] & 0xffff0000u);
                qf[2] = __uint_as_float(q2[1] << 16);
                qf[3] = __uint_as_float(q2[1] & 0xffff0000u);
#pragma unroll
                for (int cc = 0; cc < 4; ++cc)
#pragma unroll
                    for (int j = 0; j < KK; ++j)
                        sc[u][j] = fmaf(kf[cc][j], qf[cc], sc[u][j]);
            }
        }

#pragma unroll
        for (int u = 0; u < 4; ++u) {
            if (p0 + u < pend) {
                float* Ap = At + (size_t)pp[u] * PSTRIDE + pi[pidx[u]] * KK;
#pragma unroll
                for (int j = 0; j < KK; ++j) Ap[j] = sc[u][j];
            }
        }
    }
}

// ---------------------------------------------------------------------------
// K3: fused softmax(49) + V-aggregate, 2 pixels (h, h+2) per thread; 8 bf16
// window loads serve 14 (pixel,i) uses. Grid 1024 = xcd(8) x [pair16 x cg8],
// 256 thr = 128 w x 2 cs. Ot bf16. No LDS, no barriers.
// ---------------------------------------------------------------------------
__global__ __launch_bounds__(256) void aggr_kernel(
    const __hip_bfloat16* __restrict__ Vp, const float* __restrict__ At,
    __hip_bfloat16* __restrict__ Ot)
{
    const int xcd = blockIdx.x & 7;
    const int s   = blockIdx.x >> 3;        // 0..127
    const int cg  = s & 7;
    const int u   = s >> 3;                 // 0..15
    const int P   = xcd * 16 + u;           // 0..127 pair id
    const int b   = P >> 6;
    const int hpl = P & 63;
    const int ha  = (hpl >> 1) * 4 + (hpl & 1);   // pair (ha, ha+2)
    const int w   = threadIdx.x & 127;
    const int cs  = threadIdx.x >> 7;
    const int pa  = b * HWSZ + ha * WW + w;
    const int pb_ = pa + 2 * WW;

    float pra[52], prb[52];
    {
        const float4* Aa = (const float4*)(At + (size_t)pa * PSTRIDE);
        const float4* Ab = (const float4*)(At + (size_t)pb_ * PSTRIDE);
#pragma unroll
        for (int t = 0; t < 13; ++t) { ((float4*)pra)[t] = Aa[t]; ((float4*)prb)[t] = Ab[t]; }
        float ma = pra[0], mb = prb[0];
#pragma unroll
        for (int k = 1; k < K2; ++k) { ma = fmaxf(ma, pra[k]); mb = fmaxf(mb, prb[k]); }
        float sa = 0.f, sb = 0.f;
#pragma unroll
        for (int k = 0; k < K2; ++k) {
            pra[k] = __expf(pra[k] - ma); sa += pra[k];
            prb[k] = __expf(prb[k] - mb); sb += prb[k];
        }
        const float ia = 1.f / sa, ib = 1.f / sb;
#pragma unroll
        for (int k = 0; k < K2; ++k) { pra[k] *= ia; prb[k] *= ib; }
    }

    int rw[8];
#pragma unroll
    for (int t = 0; t < 8; ++t) rw[t] = clampi(ha - 6 + 2 * t, 0, HH - 1);

    const int loff = lane_off(w);
    const int c0   = cg * 8 + cs * 4;
    float acc_a[4] = {0.f, 0.f, 0.f, 0.f};
    float acc_b[4] = {0.f, 0.f, 0.f, 0.f};
#pragma unroll
    for (int cc = 0; cc < 4; ++cc) {
        const __hip_bfloat16* vch =
            Vp + (size_t)(b * CC + c0 + cc) * HH * ROWE + loff;
#pragma unroll
        for (int t = 0; t < 8; ++t) {
            float vv[8];
            unpack8(ld16(vch + (size_t)rw[t] * ROWE), vv);
            if (t < 7) {
#pragma unroll
                for (int j = 0; j < KK; ++j)
                    acc_a[cc] = fmaf(vv[j], pra[t * KK + j], acc_a[cc]);
            }
            if (t >= 1) {
#pragma unroll
                for (int j = 0; j < KK; ++j)
                    acc_b[cc] = fmaf(vv[j], prb[(t - 1) * KK + j], acc_b[cc]);
            }
        }
    }

    u32 oda[2] = { (u32)f2bf(acc_a[0]) | ((u32)f2bf(acc_a[1]) << 16),
                   (u32)f2bf(acc_a[2]) | ((u32)f2bf(acc_a[3]) << 16) };
    u32 odb[2] = { (u32)f2bf(acc_b[0]) | ((u32)f2bf(acc_b[1]) << 16),
                   (u32)f2bf(acc_b[2]) | ((u32)f2bf(acc_b[3]) << 16) };
    __builtin_memcpy(Ot + (size_t)pa * CC + c0, oda, 8);
    __builtin_memcpy(Ot + (size_t)pb_ * CC + c0, odb, 8);
}

// ---------------------------------------------------------------------------
// K4: out = Wt @ O + x. Grid 1024 = xcd(8) x [pb16 x og8]. O read as 8 bf16
// per 16B load (8 loads/thread).
// ---------------------------------------------------------------------------
__global__ __launch_bounds__(256) void wt_kernel(
    const __hip_bfloat16* __restrict__ Ot, const float* __restrict__ x,
    const float* __restrict__ Wt, float* __restrict__ out)
{
    const int xcd = blockIdx.x & 7;
    const int s   = blockIdx.x >> 3;        // 0..127
    const int pb  = xcd * 16 + (s & 15);
    const int og  = s >> 4;
    const int p   = pb * 256 + threadIdx.x;
    const int b   = p >> 14;
    const int hw  = p & 16383;
    const int o0  = og * 8;

    float fin[8];
#pragma unroll
    for (int i = 0; i < 8; ++i)
        fin[i] = x[((size_t)b * CC + o0 + i) * HWSZ + hw];

    const __hip_bfloat16* op = Ot + (size_t)p * CC;
#pragma unroll
    for (int k = 0; k < 8; ++k) {
        float oc[8];
        unpack8(ld16(op + 8 * k), oc);
#pragma unroll
        for (int cc = 0; cc < 8; ++cc) {
            const int c = 8 * k + cc;
#pragma unroll
            for (int i = 0; i < 8; ++i)
                fin[i] = fmaf(Wt[(o0 + i) * CC + c], oc[cc], fin[i]);
        }
    }

#pragma unroll
    for (int i = 0; i < 8; ++i)
        out[((size_t)b * CC + o0 + i) * HWSZ + hw] = fin[i];
}

// ---------------------------------------------------------------------------
extern "C" void kernel_launch(void* const* d_in, const int* in_sizes, int n_in,
                              void* d_out, int out_size, void* d_ws, size_t ws_size,
                              hipStream_t stream)
{
    const float* x  = (const float*)d_in[0];
    const float* Wk = (const float*)d_in[1];
    const float* Wq = (const float*)d_in[2];
    const float* Wv = (const float*)d_in[3];
    const float* Wt = (const float*)d_in[4];
    float* out = (float*)d_out;

    const size_t KP_ELEMS = (size_t)BB * CC * HH * ROWE;  // 4,587,520 bf16
    __hip_bfloat16* Kp = (__hip_bfloat16*)d_ws;
    __hip_bfloat16* Vp = Kp + KP_ELEMS;
    float* At = (float*)(Vp + KP_ELEMS);   // fp32, BB*HWSZ*52; total ws 25.2 MB
    __hip_bfloat16* Qt = (__hip_bfloat16*)d_out;  // scratch; dead before wt
    __hip_bfloat16* Ot = Kp;                      // Kp dead after score

    hipLaunchKernelGGL(kqv_kernel, dim3(1024), dim3(256), 0, stream,
                       x, Wk, Wq, Wv, Kp, Qt, Vp);
    hipLaunchKernelGGL(score_kernel, dim3(BB * HH), dim3(512), 0, stream,
                       Kp, Qt, At);
    hipLaunchKernelGGL(aggr_kernel, dim3(1024), dim3(256), 0, stream,
                       Vp, At, Ot);
    hipLaunchKernelGGL(wt_kernel, dim3(1024), dim3(256), 0, stream,
                       Ot, x, Wt, out);
}

// Round 10
// 82.449 us; speedup vs baseline: 1.3050x; 1.2038x over previous
//
#include <hip/hip_runtime.h>
#include <hip/hip_bf16.h>

#define HH 128
#define WW 128
#define HWSZ (HH * WW)   // 16384
#define CC 64
#define BB 2
#define KK 7
#define K2 49
#define ROWE 280         // bf16 elems/padded row: [Eph0 70][Eph1 70][Oph0 70][Oph1 70]

typedef unsigned int u32;

__device__ __forceinline__ int clampi(int v, int lo, int hi) {
    return v < lo ? lo : (v > hi ? hi : v);
}

__device__ __forceinline__ uint4 ld16(const __hip_bfloat16* src) {
    uint4 d; __builtin_memcpy(&d, src, 16); return d;   // 4B-aligned dwordx4
}

// 8 packed bf16 (4 dwords) -> 8 fp32. elem 2k = lo half of dword k.
__device__ __forceinline__ void unpack8(uint4 d, float* f) {
    f[0] = __uint_as_float(d.x << 16); f[1] = __uint_as_float(d.x & 0xffff0000u);
    f[2] = __uint_as_float(d.y << 16); f[3] = __uint_as_float(d.y & 0xffff0000u);
    f[4] = __uint_as_float(d.z << 16); f[5] = __uint_as_float(d.z & 0xffff0000u);
    f[6] = __uint_as_float(d.w << 16); f[7] = __uint_as_float(d.w & 0xffff0000u);
}

__device__ __forceinline__ unsigned short f2bf(float v) {
    __hip_bfloat16 b = __float2bfloat16(v);
    return *reinterpret_cast<unsigned short*>(&b);
}

// Store one K/V value into the phase-duplicated parity row + edge pads.
__device__ __forceinline__ void store_kv(__hip_bfloat16* rowp, int w, float val) {
    const int parity = w & 1, t = w >> 1;
    const int pb = parity * 140;
    __hip_bfloat16 bv = __float2bfloat16(val);
    rowp[pb + 3 + t]  = bv;        // phase0: P[t+3]
    rowp[pb + 72 + t] = bv;        // phase1: P1[t+2]
    if (w == 0) {
#pragma unroll
        for (int u = 0; u < 3; ++u) { rowp[u] = bv; rowp[140 + u] = bv; }
#pragma unroll
        for (int u = 0; u < 2; ++u) { rowp[70 + u] = bv; rowp[210 + u] = bv; }
    }
    if (w == 127) {
#pragma unroll
        for (int u = 0; u < 3; ++u) { rowp[67 + u] = bv; rowp[140 + 67 + u] = bv; }
#pragma unroll
        for (int u = 0; u < 4; ++u) { rowp[70 + 66 + u] = bv; rowp[210 + 66 + u] = bv; }
    }
}

// per-lane window offset: 7-neighbor window = first 7 elems of one aligned 16B load
__device__ __forceinline__ int lane_off(int w) {
    const int parity = w & 1, t = w >> 1, phase = t & 1;
    return parity * 140 + phase * 70 + (t - phase);   // even -> 4B-aligned bytes
}

// ---------------------------------------------------------------------------
// K1: K/Q/V = relu(W @ x). Grid 1024 = xcd(8) x [pb16 x og8].
// K,V -> bf16 phase-dup parity rows; Q -> bf16 Qt[p][64].
// ---------------------------------------------------------------------------
__global__ __launch_bounds__(256) void kqv_kernel(
    const float* __restrict__ x,  const float* __restrict__ Wk,
    const float* __restrict__ Wq, const float* __restrict__ Wv,
    __hip_bfloat16* __restrict__ Kp, __hip_bfloat16* __restrict__ Qt,
    __hip_bfloat16* __restrict__ Vp)
{
    const int xcd = blockIdx.x & 7;
    const int s   = blockIdx.x >> 3;          // 0..127
    const int pb  = xcd * 16 + (s & 15);      // 0..127
    const int og  = s >> 4;                   // 0..7
    const int p   = pb * 256 + threadIdx.x;   // 0..32767
    const int b   = p >> 14;
    const int hw  = p & 16383;
    const int h   = hw >> 7;
    const int w   = hw & 127;
    const int o0  = og * 8;
    const float* xp = x + (size_t)b * CC * HWSZ + hw;

    float aK[8], aQ[8], aV[8];
#pragma unroll
    for (int i = 0; i < 8; ++i) { aK[i] = 0.f; aQ[i] = 0.f; aV[i] = 0.f; }

#pragma unroll 4
    for (int c = 0; c < CC; ++c) {
        const float xv = xp[(size_t)c * HWSZ];
#pragma unroll
        for (int i = 0; i < 8; ++i) {
            aK[i] = fmaf(Wk[(o0 + i) * CC + c], xv, aK[i]);
            aQ[i] = fmaf(Wq[(o0 + i) * CC + c], xv, aQ[i]);
            aV[i] = fmaf(Wv[(o0 + i) * CC + c], xv, aV[i]);
        }
    }

#pragma unroll
    for (int i = 0; i < 8; ++i) {
        __hip_bfloat16* krow = Kp + ((size_t)(b * CC + o0 + i) * HH + h) * ROWE;
        __hip_bfloat16* vrow = Vp + ((size_t)(b * CC + o0 + i) * HH + h) * ROWE;
        store_kv(krow, w, fmaxf(aK[i], 0.f));
        store_kv(vrow, w, fmaxf(aV[i], 0.f));
    }

    u32 qd[4];
#pragma unroll
    for (int i = 0; i < 4; ++i)
        qd[i] = (u32)f2bf(fmaxf(aQ[2 * i], 0.f)) |
                ((u32)f2bf(fmaxf(aQ[2 * i + 1], 0.f)) << 16);
    __builtin_memcpy(Qt + (size_t)p * CC + o0, qd, 16);   // 16B aligned
}

// ---------------------------------------------------------------------------
// K2: FUSED scores + softmax + V-aggregate. Grid 1024 = xcd(8) x [bh32 x wseg4],
// 256 thr: px = (tid&15)|((tid>>7)<<4) (0..31), cq = (tid>>4)&7 (8 channels).
// Phase A: partial sc[49] over cq's 8 channels (7 window ld16/ch).
// Reduce: shfl_xor(16)+shfl_xor(32) sums 4 cqs/wave -> 2 LDS slices -> 1 barrier.
// Softmax: per thread (redundant x8, identical order -> deterministic).
// Phase B: aggregate cq's 8 out-channels, one 16B bf16 store.
// ---------------------------------------------------------------------------
__global__ __launch_bounds__(256) void attn_kernel(
    const __hip_bfloat16* __restrict__ Kp, const __hip_bfloat16* __restrict__ Qt,
    const __hip_bfloat16* __restrict__ Vp, __hip_bfloat16* __restrict__ Ot)
{
    __shared__ float part[2][K2][33];

    const int xcd  = blockIdx.x & 7;
    const int s    = blockIdx.x >> 3;       // 0..127
    const int bh   = xcd * 32 + (s >> 2);   // 0..255
    const int wseg = s & 3;
    const int b    = bh >> 7;
    const int h    = bh & 127;

    const int tid = threadIdx.x;
    const int px  = (tid & 15) | ((tid >> 7) << 4);   // 0..31
    const int cq  = (tid >> 4) & 7;                   // 0..7
    const int w   = wseg * 32 + px;                   // 0..127
    const int p   = b * HWSZ + h * WW + w;
    const int c0  = cq * 8;

    int hn[KK];
#pragma unroll
    for (int i = 0; i < KK; ++i) hn[i] = clampi(h + 2 * i - 6, 0, HH - 1);

    const int loff = lane_off(w);
    const size_t cstride = (size_t)HH * ROWE;
    const __hip_bfloat16* Kc = Kp + (size_t)(b * CC + c0) * cstride + loff;
    const __hip_bfloat16* Vc = Vp + (size_t)(b * CC + c0) * cstride + loff;

    // Q for this thread's 8 channels: one 16B load
    float qf[8];
    unpack8(ld16(Qt + (size_t)p * CC + c0), qf);

    // ---- Phase A: partial scores over 8 channels ----
    float sc[K2];
#pragma unroll
    for (int k = 0; k < K2; ++k) sc[k] = 0.f;

    for (int ci = 0; ci < 8; ++ci) {
        uint4 kd[KK];
        const __hip_bfloat16* base = Kc + (size_t)ci * cstride;
#pragma unroll
        for (int i = 0; i < KK; ++i) kd[i] = ld16(base + (size_t)hn[i] * ROWE);
        const float qv = qf[ci];
#pragma unroll
        for (int i = 0; i < KK; ++i) {
            float kf[8];
            unpack8(kd[i], kf);
#pragma unroll
            for (int j = 0; j < KK; ++j)
                sc[i * KK + j] = fmaf(kf[j], qv, sc[i * KK + j]);
        }
    }

    // ---- cq-reduction: 4 cqs per wave via shfl, then 2 slices via LDS ----
#pragma unroll
    for (int k = 0; k < K2; ++k) sc[k] += __shfl_xor(sc[k], 16, 64);
#pragma unroll
    for (int k = 0; k < K2; ++k) sc[k] += __shfl_xor(sc[k], 32, 64);

    const int sl = (tid >> 6) & 1;          // wave's cq-set (0: cq0-3, 1: cq4-7)
    if (((tid >> 4) & 3) == 0) {            // one writer lane set per wave
#pragma unroll
        for (int k = 0; k < K2; ++k) part[sl][k][px] = sc[k];
    }
    __syncthreads();

    // ---- softmax (per thread, redundant x8, deterministic) ----
#pragma unroll
    for (int k = 0; k < K2; ++k) sc[k] = part[0][k][px] + part[1][k][px];
    float m = sc[0];
#pragma unroll
    for (int k = 1; k < K2; ++k) m = fmaxf(m, sc[k]);
    float sum = 0.f;
#pragma unroll
    for (int k = 0; k < K2; ++k) { sc[k] = __expf(sc[k] - m); sum += sc[k]; }
    const float inv = 1.f / sum;
#pragma unroll
    for (int k = 0; k < K2; ++k) sc[k] *= inv;

    // ---- Phase B: V-aggregate for this thread's 8 output channels ----
    unsigned short ob[8];
    for (int ci = 0; ci < 8; ++ci) {
        uint4 vd[KK];
        const __hip_bfloat16* base = Vc + (size_t)ci * cstride;
#pragma unroll
        for (int i = 0; i < KK; ++i) vd[i] = ld16(base + (size_t)hn[i] * ROWE);
        float acc = 0.f;
#pragma unroll
        for (int i = 0; i < KK; ++i) {
            float vf[8];
            unpack8(vd[i], vf);
#pragma unroll
            for (int j = 0; j < KK; ++j)
                acc = fmaf(vf[j], sc[i * KK + j], acc);
        }
        ob[ci] = f2bf(acc);
    }

    u32 od[4];
#pragma unroll
    for (int i = 0; i < 4; ++i)
        od[i] = (u32)ob[2 * i] | ((u32)ob[2 * i + 1] << 16);
    __builtin_memcpy(Ot + (size_t)p * CC + c0, od, 16);   // 16B aligned
}

// ---------------------------------------------------------------------------
// K3: out = Wt @ O + x. Grid 1024 = xcd(8) x [pb16 x og8]. O read as 8 bf16
// per 16B load.
// ---------------------------------------------------------------------------
__global__ __launch_bounds__(256) void wt_kernel(
    const __hip_bfloat16* __restrict__ Ot, const float* __restrict__ x,
    const float* __restrict__ Wt, float* __restrict__ out)
{
    const int xcd = blockIdx.x & 7;
    const int s   = blockIdx.x >> 3;        // 0..127
    const int pb  = xcd * 16 + (s & 15);
    const int og  = s >> 4;
    const int p   = pb * 256 + threadIdx.x;
    const int b   = p >> 14;
    const int hw  = p & 16383;
    const int o0  = og * 8;

    float fin[8];
#pragma unroll
    for (int i = 0; i < 8; ++i)
        fin[i] = x[((size_t)b * CC + o0 + i) * HWSZ + hw];

    const __hip_bfloat16* op = Ot + (size_t)p * CC;
#pragma unroll
    for (int k = 0; k < 8; ++k) {
        float oc[8];
        unpack8(ld16(op + 8 * k), oc);
#pragma unroll
        for (int cc = 0; cc < 8; ++cc) {
            const int c = 8 * k + cc;
#pragma unroll
            for (int i = 0; i < 8; ++i)
                fin[i] = fmaf(Wt[(o0 + i) * CC + c], oc[cc], fin[i]);
        }
    }

#pragma unroll
    for (int i = 0; i < 8; ++i)
        out[((size_t)b * CC + o0 + i) * HWSZ + hw] = fin[i];
}

// ---------------------------------------------------------------------------
extern "C" void kernel_launch(void* const* d_in, const int* in_sizes, int n_in,
                              void* d_out, int out_size, void* d_ws, size_t ws_size,
                              hipStream_t stream)
{
    const float* x  = (const float*)d_in[0];
    const float* Wk = (const float*)d_in[1];
    const float* Wq = (const float*)d_in[2];
    const float* Wv = (const float*)d_in[3];
    const float* Wt = (const float*)d_in[4];
    float* out = (float*)d_out;

    const size_t KP_ELEMS = (size_t)BB * CC * HH * ROWE;  // 4,587,520 bf16
    const size_t QT_ELEMS = (size_t)BB * HWSZ * CC;       // 2,097,152 bf16
    __hip_bfloat16* Kp = (__hip_bfloat16*)d_ws;
    __hip_bfloat16* Vp = Kp + KP_ELEMS;
    __hip_bfloat16* Qt = Vp + KP_ELEMS;
    __hip_bfloat16* Ot = Qt + QT_ELEMS;                   // total ws 26.8 MB

    hipLaunchKernelGGL(kqv_kernel, dim3(1024), dim3(256), 0, stream,
                       x, Wk, Wq, Wv, Kp, Qt, Vp);
    hipLaunchKernelGGL(attn_kernel, dim3(1024), dim3(256), 0, stream,
                       Kp, Qt, Vp, Ot);
    hipLaunchKernelGGL(wt_kernel, dim3(1024), dim3(256), 0, stream,
                       Ot, x, Wt, out);
}